// Round 22
// baseline (500.848 us; speedup 1.0000x reference)
//
#include <hip/hip_runtime.h>

#define B_ 8
#define C_ 512
#define T_ 2048
#define I_ 256
#define TP_ (T_ + 4)   // padded time rows (2 each side) for shifted tconv reads

typedef _Float16 f16x8 __attribute__((ext_vector_type(8)));
typedef float f32x4 __attribute__((ext_vector_type(4)));
typedef unsigned short u16;
typedef unsigned short u16x4 __attribute__((ext_vector_type(4)));

__device__ __forceinline__ u16 f2h(float f) {
    _Float16 h = (_Float16)f;
    return *(u16*)&h;
}
__device__ __forceinline__ float h2f(u16 u) {
    _Float16 h = *(_Float16*)&u;
    return (float)h;
}

#define AS1 __attribute__((address_space(1)))
#define AS3 __attribute__((address_space(3)))
__device__ __forceinline__ void gload16(const u16* g, u16* l) {
    __builtin_amdgcn_global_load_lds((const AS1 void*)(const void*)g,
                                     (AS3 void*)(void*)l, 16, 0, 0);
}

// ---------------------------------------------------------------------------
// fp16 MFMA GEMM: out[z][m][n] = sum_k A[zw][m][k] * B[zb][n][k] (+ bias[zw][m])
//   zw = z / aZdiv (weight index), zb = z % bZmod (B-operand batch index).
//   TCONV: B row offset (kh-1)*d, kh = k0>>9; d = dShift, or 1+(z>>3) if
//   dShift==0 (merged dual-dilation dispatch). Output always indexed by z.
// Tile 128x128, BK=64, 256 thr = 4 waves. LDS slot^(row&7) swizzle.
// WMODE bits: 1 = f32 normal (Cf), 2 = f16 normal (Cn), 4 = f16 transposed (Ct).
// ---------------------------------------------------------------------------
template <int WMODE, bool BIAS, bool RELU, bool TCONV>
__global__ __launch_bounds__(256) void mfma_gemm(
    const u16* __restrict__ A, long aB, int aZdiv, int lda,
    const u16* __restrict__ Bm, long bB, int ldb, int bZmod,
    const float* __restrict__ bias, int biasStride,
    float* __restrict__ Cf, u16* __restrict__ Cn, long cB, int ldc,
    u16* __restrict__ Ct, long ctB, int ldct, int ctOff,
    int K, int dShift)
{
    __shared__ u16 sA[128 * 64];
    __shared__ u16 sB[128 * 64];
    const int z = blockIdx.z;
    const int zw = z / aZdiv;
    const int zb = z % bZmod;
    const int m0 = blockIdx.y * 128, n0 = blockIdx.x * 128;
    const int tid = threadIdx.x;
    const int lane = tid & 63, wv = tid >> 6;
    const int wm = wv >> 1, wn = wv & 1;
    const int l15 = lane & 15, l4 = lane >> 4;

    const u16* Ab = A + (long)zw * aB + (long)m0 * lda;
    const u16* Bb = Bm + (long)zb * bB + (long)n0 * ldb;

    const int srow = wv * 32 + (lane >> 3);
    const int sk16 = (lane & 7) ^ (lane >> 3);

    f32x4 acc[4][4];
    #pragma unroll
    for (int i = 0; i < 4; ++i)
        #pragma unroll
        for (int j = 0; j < 4; ++j) acc[i][j] = (f32x4){0.f, 0.f, 0.f, 0.f};

    for (int k0 = 0; k0 < K; k0 += 64) {
        int bCol = k0;
        int rOff = 0;
        if (TCONV) {
            const int kh = k0 >> 9;
            const int d = dShift ? dShift : 1 + (z >> 3);
            rOff = (kh - 1) * d;
            bCol = k0 & 511;
        }
        #pragma unroll
        for (int ch = 0; ch < 4; ++ch) {
            gload16(Ab + (long)(srow + ch * 8) * lda + k0 + sk16 * 8,
                    &sA[wv * 2048 + ch * 512]);
            gload16(Bb + (long)(srow + ch * 8 + rOff) * ldb + bCol + sk16 * 8,
                    &sB[wv * 2048 + ch * 512]);
        }
        __syncthreads();
        #pragma unroll
        for (int kk = 0; kk < 2; ++kk) {
            f16x8 af[4], bfr[4];
            #pragma unroll
            for (int f = 0; f < 4; ++f) {
                const int ra = wm * 64 + f * 16 + l15;
                af[f] = *(const f16x8*)&sA[ra * 64 + ((((kk << 2) | l4) ^ (ra & 7)) << 3)];
                const int rb = wn * 64 + f * 16 + l15;
                bfr[f] = *(const f16x8*)&sB[rb * 64 + ((((kk << 2) | l4) ^ (rb & 7)) << 3)];
            }
            #pragma unroll
            for (int mi = 0; mi < 4; ++mi)
                #pragma unroll
                for (int ni = 0; ni < 4; ++ni)
                    acc[mi][ni] = __builtin_amdgcn_mfma_f32_16x16x32_f16(
                        af[mi], bfr[ni], acc[mi][ni], 0, 0, 0);
        }
        __syncthreads();
    }

    #pragma unroll
    for (int mi = 0; mi < 4; ++mi) {
        const int mb = m0 + wm * 64 + mi * 16 + l4 * 4;
        float bv[4] = {0.f, 0.f, 0.f, 0.f};
        if (BIAS) {
            const float* bp = bias + (long)zw * biasStride;
            #pragma unroll
            for (int r = 0; r < 4; ++r) bv[r] = bp[mb + r];
        }
        #pragma unroll
        for (int ni = 0; ni < 4; ++ni) {
            const int nb = n0 + wn * 64 + ni * 16 + l15;
            float v[4];
            #pragma unroll
            for (int r = 0; r < 4; ++r) {
                v[r] = acc[mi][ni][r] + bv[r];
                if (RELU) v[r] = fmaxf(v[r], 0.f);
            }
            if (WMODE & 1) {
                #pragma unroll
                for (int r = 0; r < 4; ++r)
                    Cf[(long)z * cB + (long)(mb + r) * ldc + nb] = v[r];
            }
            if (WMODE & 2) {
                #pragma unroll
                for (int r = 0; r < 4; ++r)
                    Cn[(long)z * cB + (long)(mb + r) * ldc + nb] = f2h(v[r]);
            }
            if (WMODE & 4) {
                u16x4 pk;
                #pragma unroll
                for (int r = 0; r < 4; ++r) pk[r] = f2h(v[r]);
                *(u16x4*)&Ct[(long)z * ctB + (long)nb * ldct + ctOff + mb] = pk;
            }
        }
    }
}

// ---------------------------------------------------------------------------
// Flash attention v7s: R16-proven split-KV body (206 us) + T5 s_setprio
// around the MFMA clusters. Mechanism: 2 independent blocks co-resident/CU
// at different phases -> scheduler can prefer the MFMA-entering block's
// waves over the staging block's (attn-positive per m191; GEMM-lockstep
// null per m190 so GEMMs left untouched).
// ---------------------------------------------------------------------------
__global__ __launch_bounds__(512) void flash_attn(
    const u16* __restrict__ thA, const u16* __restrict__ phA,
    const u16* __restrict__ gxA, u16* __restrict__ oH,
    float* __restrict__ mH, float* __restrict__ lH)
{
    __shared__ u16 sK[64 * 256];     // [s][k]  32 KB, slot^(s&7) swizzle
    __shared__ u16 sV[256 * 64];     // [dv][s] 32 KB, slot^(dv&7) swizzle
    __shared__ u16 sP[8 * 16 * 64];  // per-wave [t][s] 16 KB, slot^(t&7)

    const int flat = (blockIdx.z * 24 + blockIdx.y) * 16 + blockIdx.x; // 0..767
    const int swz = (flat & 7) * 96 + (flat >> 3);   // 768 = 8 XCD x 96
    const int u = swz % 384;
    const int qb = u & 15, z = u >> 4;
    const int half = swz / 384;
    const int t0 = qb * 128;
    const int sBase = half * (T_ / 2);
    const int tid = threadIdx.x;
    const int lane = tid & 63, wv = tid >> 6;
    const int l15 = lane & 15, l4 = lane >> 4;

    const u16* Qz = thA + (long)z * (T_ * I_);
    const u16* Kz = phA + (long)z * (T_ * I_);
    const u16* Vz = gxA + (long)z * ((long)I_ * T_);

    // Q fragments in regs: rows t0 + wv*16 + l15, k = ks*32 + l4*8
    f16x8 qf[8];
    {
        const u16* qrow = Qz + (long)(t0 + wv * 16 + l15) * I_ + l4 * 8;
        #pragma unroll
        for (int ks = 0; ks < 8; ++ks) qf[ks] = *(const f16x8*)(qrow + ks * 32);
    }

    f32x4 oacc[16];
    #pragma unroll
    for (int i = 0; i < 16; ++i) oacc[i] = (f32x4){0.f, 0.f, 0.f, 0.f};
    float mrun[4] = {-1e30f, -1e30f, -1e30f, -1e30f};
    float lrun[4] = {0.f, 0.f, 0.f, 0.f};

    const int krow = tid >> 5;                    // + is*16
    const int kk16 = (tid & 31) ^ (krow & 7);
    const int vrow = tid >> 3;                    // + is*64
    const int vk16 = (tid & 7) ^ (vrow & 7);

    for (int s0 = sBase; s0 < sBase + T_ / 2; s0 += 64) {
        #pragma unroll
        for (int is = 0; is < 4; ++is) {
            gload16(Kz + (long)(s0 + is * 16 + krow) * I_ + kk16 * 8,
                    &sK[is * 4096 + tid * 8]);
            gload16(Vz + (long)(is * 64 + vrow) * T_ + s0 + vk16 * 8,
                    &sV[is * 4096 + tid * 8]);
        }
        __syncthreads();

        // S = Q K^T: rows t (wave's 16), cols s (64) = 4 n-frags
        f32x4 sacc[4];
        #pragma unroll
        for (int nf = 0; nf < 4; ++nf) sacc[nf] = (f32x4){0.f, 0.f, 0.f, 0.f};
        __builtin_amdgcn_s_setprio(1);
        #pragma unroll
        for (int nf = 0; nf < 4; ++nf) {
            const int srow = nf * 16 + l15;
            #pragma unroll
            for (int ks = 0; ks < 8; ++ks) {
                f16x8 kf = *(const f16x8*)&sK[srow * 256 + ((((ks << 2) | l4) ^ (srow & 7)) << 3)];
                sacc[nf] = __builtin_amdgcn_mfma_f32_16x16x32_f16(qf[ks], kf, sacc[nf], 0, 0, 0);
            }
        }
        __builtin_amdgcn_s_setprio(0);

        // online softmax; C/D row = l4*4+r, col = l15 + nf*16
        float scale[4];
        #pragma unroll
        for (int r = 0; r < 4; ++r) {
            float v0 = fmaxf(fmaxf(sacc[0][r], sacc[1][r]),
                             fmaxf(sacc[2][r], sacc[3][r]));
            #pragma unroll
            for (int o = 8; o; o >>= 1) v0 = fmaxf(v0, __shfl_xor(v0, o, 64));
            const float mnew = fmaxf(mrun[r], v0);
            scale[r] = __expf(mrun[r] - mnew);
            mrun[r] = mnew;
        }
        float rsum[4] = {0.f, 0.f, 0.f, 0.f};
        #pragma unroll
        for (int nf = 0; nf < 4; ++nf) {
            #pragma unroll
            for (int r = 0; r < 4; ++r) {
                const float p = __expf(sacc[nf][r] - mrun[r]);
                rsum[r] += p;
                const int tl = l4 * 4 + r;
                const int sl = l15 + nf * 16;
                sP[wv * 1024 + tl * 64 + ((((sl >> 3) ^ (tl & 7)) << 3) | (sl & 7))] = f2h(p);
            }
        }
        #pragma unroll
        for (int r = 0; r < 4; ++r) {
            #pragma unroll
            for (int o = 8; o; o >>= 1) rsum[r] += __shfl_xor(rsum[r], o, 64);
            lrun[r] = lrun[r] * scale[r] + rsum[r];
        }
        #pragma unroll
        for (int nf = 0; nf < 16; ++nf)
            #pragma unroll
            for (int r = 0; r < 4; ++r) oacc[nf][r] *= scale[r];

        // PV: A = P (row t = l15, k = s), B = V (row dv, k = s)
        f16x8 pa[2];
        #pragma unroll
        for (int kk = 0; kk < 2; ++kk)
            pa[kk] = *(const f16x8*)&sP[wv * 1024 + l15 * 64 + ((((kk << 2) | l4) ^ (l15 & 7)) << 3)];
        __builtin_amdgcn_s_setprio(1);
        #pragma unroll
        for (int nf = 0; nf < 16; ++nf) {
            const int dvr = nf * 16 + l15;
            #pragma unroll
            for (int kk = 0; kk < 2; ++kk) {
                f16x8 vf = *(const f16x8*)&sV[dvr * 64 + ((((kk << 2) | l4) ^ (dvr & 7)) << 3)];
                oacc[nf] = __builtin_amdgcn_mfma_f32_16x16x32_f16(pa[kk], vf, oacc[nf], 0, 0, 0);
            }
        }
        __builtin_amdgcn_s_setprio(0);
        __syncthreads();
    }

    // store UNNORMALIZED partials: oH[half][z][t][dv] (f16), mH/lH[half][z][t]
    #pragma unroll
    for (int r = 0; r < 4; ++r) {
        const int t = t0 + wv * 16 + l4 * 4 + r;
        const long row = ((long)half * 24 + z) * T_ + t;
        u16* dst = oH + row * I_ + l15;
        #pragma unroll
        for (int nf = 0; nf < 16; ++nf)
            dst[nf * 16] = f2h(oacc[nf][r]);
        if (l15 == 0) { mH[row] = mrun[r]; lH[row] = lrun[r]; }
    }
}

// combine: YT[b][t][br*I+dv] = (o0*e^{m0-m} + o1*e^{m1-m}) / (l0*e^{m0-m}+l1*e^{m1-m})
__global__ __launch_bounds__(256) void combine_kernel(
    const u16* __restrict__ oH, const float* __restrict__ mH,
    const float* __restrict__ lH, u16* __restrict__ YT)
{
    const long idx = (long)blockIdx.x * 256 + threadIdx.x;  // 24*T*(I/8)
    const int z = (int)(idx / (T_ * (I_ / 8)));
    const long rem = idx % (T_ * (I_ / 8));
    const int t = (int)(rem / (I_ / 8));
    const int dv0 = (int)(rem % (I_ / 8)) * 8;
    const long row0 = (long)z * T_ + t;
    const long row1 = ((long)24 + z) * T_ + t;
    const float m0 = mH[row0], m1 = mH[row1];
    const float l0 = lH[row0], l1 = lH[row1];
    const float m = fmaxf(m0, m1);
    const float a0 = __expf(m0 - m), a1 = __expf(m1 - m);
    const float inv = 1.f / (l0 * a0 + l1 * a1);
    const uint4 p0 = *(const uint4*)&oH[row0 * I_ + dv0];
    const uint4 p1 = *(const uint4*)&oH[row1 * I_ + dv0];
    const u16* b0 = (const u16*)&p0;
    const u16* b1 = (const u16*)&p1;
    uint4 ov;
    u16* bo = (u16*)&ov;
    #pragma unroll
    for (int j = 0; j < 8; ++j)
        bo[j] = f2h((h2f(b0[j]) * a0 + h2f(b1[j]) * a1) * inv);
    const int br = z >> 3, b = z & 7;
    *(uint4*)&YT[((long)b * T_ + t) * (3 * I_) + br * I_ + dv0] = ov;
}

// ---------------------------------------------------------------------------
__global__ __launch_bounds__(256) void to_f16(
    const float* __restrict__ s, u16* __restrict__ d, long n4)
{
    const long i = (long)blockIdx.x * 256 + threadIdx.x;
    if (i >= n4) return;
    const float4 v = ((const float4*)s)[i];
    u16x4 pk = {f2h(v.x), f2h(v.y), f2h(v.z), f2h(v.w)};
    ((u16x4*)d)[i] = pk;
}

__global__ __launch_bounds__(256) void peT_kernel(float* __restrict__ peT)
{
    const int idx = blockIdx.x * 256 + threadIdx.x;
    const int c = idx & (C_ - 1), t = idx >> 9;
    const float i2 = (float)(c & ~1);
    const float freq = expf(-(9.210340371976184f / (float)C_) * i2);
    const float ang = (float)t * freq;
    peT[idx] = (c & 1) ? cosf(ang) : sinf(ang);
}

__global__ __launch_bounds__(256) void xpose_add(
    const float* __restrict__ x, const float* __restrict__ peT,
    u16* __restrict__ xpeT)
{
    __shared__ float tile[64][65];
    const int b = blockIdx.z;
    const int t0 = blockIdx.x * 64, c0 = blockIdx.y * 64;
    const int rr = threadIdx.x >> 4, cc4 = (threadIdx.x & 15) << 2;
    #pragma unroll
    for (int p = 0; p < 4; ++p) {
        const int row = rr + p * 16;
        const float4 v = *(const float4*)&x[((long)b * C_ + c0 + row) * T_ + t0 + cc4];
        tile[row][cc4 + 0] = v.x; tile[row][cc4 + 1] = v.y;
        tile[row][cc4 + 2] = v.z; tile[row][cc4 + 3] = v.w;
    }
    __syncthreads();
    #pragma unroll
    for (int p = 0; p < 4; ++p) {
        const int tt = rr + p * 16;
        const int gt = t0 + tt;
        const float4 pv = *(const float4*)&peT[(long)gt * C_ + c0 + cc4];
        u16x4 pk = {f2h(tile[cc4 + 0][tt] + pv.x),
                    f2h(tile[cc4 + 1][tt] + pv.y),
                    f2h(tile[cc4 + 2][tt] + pv.z),
                    f2h(tile[cc4 + 3][tt] + pv.w)};
        *(u16x4*)&xpeT[((long)b * T_ + gt) * C_ + c0 + cc4] = pk;
    }
}

__global__ __launch_bounds__(256) void stats_kernel(
    const float* __restrict__ wy, float* __restrict__ mean,
    float* __restrict__ rstd)
{
    __shared__ float sm[8];
    const int o = blockIdx.x, tid = threadIdx.x;
    float s = 0.f, ss = 0.f;
    for (int idx = tid; idx < B_ * T_; idx += 256) {
        const int b = idx >> 11, t = idx & (T_ - 1);
        const float vv = wy[((long)b * C_ + o) * T_ + t];
        s += vv; ss += vv * vv;
    }
    #pragma unroll
    for (int off = 32; off; off >>= 1) {
        s += __shfl_xor(s, off, 64);
        ss += __shfl_xor(ss, off, 64);
    }
    if ((tid & 63) == 0) { sm[tid >> 6] = s; sm[4 + (tid >> 6)] = ss; }
    __syncthreads();
    if (tid == 0) {
        s = sm[0] + sm[1] + sm[2] + sm[3];
        ss = sm[4] + sm[5] + sm[6] + sm[7];
        const float mu = s / (float)(B_ * T_);
        const float var = ss / (float)(B_ * T_) - mu * mu;
        mean[o] = mu;
        rstd[o] = rsqrtf(var + 1e-5f);
    }
}

__global__ __launch_bounds__(256) void final_kernel(
    float* __restrict__ out, const u16* __restrict__ x1n,
    const float* __restrict__ mean, const float* __restrict__ rstd,
    const float* __restrict__ gamma, const float* __restrict__ beta)
{
    const long i4 = (long)blockIdx.x * 256 + threadIdx.x;
    const long i = i4 * 4;
    const int c = (int)((i / T_) & (C_ - 1));
    const float4 w = ((const float4*)out)[i4];
    const uint2 xv = ((const uint2*)x1n)[i4];
    const u16* xb = (const u16*)&xv;
    const float mu = mean[c];
    const float a = rstd[c] * gamma[c];
    const float bb = beta[c];
    float4 r;
    r.x = (w.x - mu) * a + bb + h2f(xb[0]);
    r.y = (w.y - mu) * a + bb + h2f(xb[1]);
    r.z = (w.z - mu) * a + bb + h2f(xb[2]);
    r.w = (w.w - mu) * a + bb + h2f(xb[3]);
    ((float4*)out)[i4] = r;
}

// ---------------------------------------------------------------------------
extern "C" void kernel_launch(void* const* d_in, const int* in_sizes, int n_in,
                              void* d_out, int out_size, void* d_ws, size_t ws_size,
                              hipStream_t stream)
{
    const float* x    = (const float*)d_in[0];
    const float* w_tr = (const float*)d_in[1];
    const float* b_tr = (const float*)d_in[2];
    const float* w_tc = (const float*)d_in[3];
    const float* w_g  = (const float*)d_in[4];
    const float* b_g  = (const float*)d_in[5];
    const float* w_th = (const float*)d_in[6];
    const float* b_th = (const float*)d_in[7];
    const float* w_ph = (const float*)d_in[8];
    const float* b_ph = (const float*)d_in[9];
    const float* w_W  = (const float*)d_in[10];
    const float* b_W  = (const float*)d_in[11];
    const float* gamma = (const float*)d_in[12];
    const float* beta  = (const float*)d_in[13];
    float* out = (float*)d_out;

    char* pp = (char*)d_ws;
    auto nextp = [&](long bytes) { char* r = pp; pp += (bytes + 255) & ~255L; return r; };
    const long TC  = (long)T_ * C_;
    const long CT  = (long)C_ * T_;
    const long TPC = (long)TP_ * C_;   // padded slab batch stride
    const long TI  = (long)T_ * I_;
    const long IT  = (long)I_ * T_;

    float* peT  = (float*)nextp(4L * T_ * C_);
    u16* xpeT   = (u16*)nextp(2L * B_ * TC);
    u16* x1n    = (u16*)nextp(2L * B_ * CT);
    u16* txAll  = (u16*)nextp(2L * 3 * B_ * TPC);  // (br, b, T+4, C), rows 2..T+1 valid
    u16* gxAll  = (u16*)nextp(2L * 3 * B_ * IT);   // (z, I, T)
    u16* thAll  = (u16*)nextp(2L * 3 * B_ * TI);   // (z, T, I); phAll contiguous after
    u16* phAll  = (u16*)nextp(2L * 3 * B_ * TI);
    u16* YT     = (u16*)nextp(2L * B_ * T_ * 3 * I_);
    u16* oH     = (u16*)nextp(2L * 2 * 24 * T_ * I_);   // split-KV partials
    float* mH   = (float*)nextp(4L * 2 * 24 * T_);
    float* lH   = (float*)nextp(4L * 2 * 24 * T_);
    u16* w_trb  = (u16*)nextp(2L * C_ * C_);
    u16* w_tcb  = (u16*)nextp(2L * 2 * C_ * 3 * C_);
    u16* w_gb   = (u16*)nextp(2L * 3 * I_ * C_);
    u16* w_thph = (u16*)nextp(2L * 6 * I_ * C_);   // [th(3,I,C); ph(3,I,C)]
    u16* w_Wb   = (u16*)nextp(2L * C_ * 3 * I_);
    float* biasAll = (float*)nextp(4L * 6 * I_);   // [b_th(3,I); b_ph(3,I)]
    float* meanb = (float*)nextp(4L * C_);
    float* rstdb = (float*)nextp(4L * C_);

    u16* slab0 = txAll;                 // tconv d=1 output (z=0..7)
    u16* slab2 = txAll + 2L * B_ * TPC; // x1 (branch 2 input + tconv B operand)

    auto cvt = [&](const float* s, u16* d, long n) {
        to_f16<<<(int)((n / 4 + 255) / 256), 256, 0, stream>>>(s, d, n / 4);
    };
    cvt(w_tr, w_trb, (long)C_ * C_);
    cvt(w_tc, w_tcb, 2L * C_ * 3 * C_);
    cvt(w_g,  w_gb,  3L * I_ * C_);
    cvt(w_th, w_thph, 3L * I_ * C_);
    cvt(w_ph, w_thph + 3L * I_ * C_, 3L * I_ * C_);
    cvt(w_W,  w_Wb,  (long)C_ * 3 * I_);
    hipMemcpyAsync(biasAll, b_th, 3L * I_ * 4, hipMemcpyDeviceToDevice, stream);
    hipMemcpyAsync(biasAll + 3 * I_, b_ph, 3L * I_ * 4, hipMemcpyDeviceToDevice, stream);

    peT_kernel<<<(T_ * C_) / 256, 256, 0, stream>>>(peT);
    xpose_add<<<dim3(T_ / 64, C_ / 64, B_), 256, 0, stream>>>(x, peT, xpeT);

    // zero x1 slab so its 2-row pads are 0 for shifted tconv reads
    hipMemsetAsync(slab2, 0, 2L * B_ * TPC, stream);

    // x1 = relu(w_tr @ xpe + b_tr) -> x1n (C,T) + padded slab2 (T,C at rows+2)
    mfma_gemm<6, true, true, false><<<dim3(16, 4, 8), 256, 0, stream>>>(
        w_trb, 0, 1, C_, xpeT, TC, C_, 9999, b_tr, 0,
        nullptr, x1n, CT, T_, slab2 + 2 * C_, TPC, C_, 0, C_, 0);

    // temporal convs MERGED: z = (d-1)*8 + b, grid.z = 16 (1024 blocks, 4/CU)
    mfma_gemm<4, false, false, true><<<dim3(16, 4, 16), 256, 0, stream>>>(
        w_tcb, (long)C_ * 3 * C_, 8, 3 * C_, slab2 + 2 * C_, TPC, C_, 8, nullptr, 0,
        nullptr, nullptr, 0, 0, slab0 + 2 * C_, TPC, C_, 0, 3 * C_, 0);

    // gx projection (grid.z = 24)
    mfma_gemm<2, true, false, false><<<dim3(16, 2, 24), 256, 0, stream>>>(
        w_gb, (long)I_ * C_, 8, C_, txAll + 2 * C_, TPC, C_, 9999, b_g, I_,
        nullptr, gxAll, IT, T_, nullptr, 0, 0, 0, C_, 0);

    // th+ph MERGED: z = proj*24 + br*8 + b, grid.z = 48 (1536 blocks, 6/CU)
    mfma_gemm<4, true, false, false><<<dim3(16, 2, 48), 256, 0, stream>>>(
        w_thph, (long)I_ * C_, 8, C_, txAll + 2 * C_, TPC, C_, 24, biasAll, I_,
        nullptr, nullptr, 0, 0, thAll, TI, I_, 0, C_, 0);

    // fused attention, split-KV (768 balanced blocks) + combine
    flash_attn<<<dim3(16, 24, 2), 512, 0, stream>>>(thAll, phAll, gxAll, oH, mH, lH);
    combine_kernel<<<(int)(24L * T_ * (I_ / 8) / 256), 256, 0, stream>>>(oH, mH, lH, YT);

    // wy = w_W @ Y + b_W -> d_out (f32)
    mfma_gemm<1, true, false, false><<<dim3(16, 4, 8), 256, 0, stream>>>(
        w_Wb, 0, 1, 3 * I_, YT, (long)T_ * 3 * I_, 3 * I_, 9999, b_W, 0,
        out, nullptr, CT, T_, nullptr, 0, 0, 0, 3 * I_, 0);

    stats_kernel<<<C_, 256, 0, stream>>>(out, meanb, rstdb);
    final_kernel<<<(int)(B_ * C_ * T_ / 4 / 256), 256, 0, stream>>>(
        out, x1n, meanb, rstdb, gamma, beta);
}

// Round 23
// 476.157 us; speedup vs baseline: 1.0519x; 1.0519x over previous
//
#include <hip/hip_runtime.h>

#define B_ 8
#define C_ 512
#define T_ 2048
#define I_ 256
#define TP_ (T_ + 4)   // padded time rows (2 each side) for shifted tconv reads

typedef _Float16 f16x8 __attribute__((ext_vector_type(8)));
typedef float f32x4 __attribute__((ext_vector_type(4)));
typedef unsigned short u16;
typedef unsigned short u16x4 __attribute__((ext_vector_type(4)));

__device__ __forceinline__ u16 f2h(float f) {
    _Float16 h = (_Float16)f;
    return *(u16*)&h;
}
__device__ __forceinline__ float h2f(u16 u) {
    _Float16 h = *(_Float16*)&u;
    return (float)h;
}

#define AS1 __attribute__((address_space(1)))
#define AS3 __attribute__((address_space(3)))
__device__ __forceinline__ void gload16(const u16* g, u16* l) {
    __builtin_amdgcn_global_load_lds((const AS1 void*)(const void*)g,
                                     (AS3 void*)(void*)l, 16, 0, 0);
}

// ---------------------------------------------------------------------------
// fp16 MFMA GEMM: out[z][m][n] = sum_k A[zw][m][k] * B[zb][n][k] (+ bias[zw][m])
//   zw = z / aZdiv (weight index), zb = z % bZmod (B-operand batch index).
//   TCONV: B row offset (kh-1)*d, kh = k0>>9; d = dShift, or 1+(z>>3) if
//   dShift==0 (merged dual-dilation dispatch). Output always indexed by z.
// Tile 128x128, BK=64, 256 thr = 4 waves. LDS slot^(row&7) swizzle.
// WMODE bits: 1 = f32 normal (Cf), 2 = f16 normal (Cn), 4 = f16 transposed (Ct).
// ---------------------------------------------------------------------------
template <int WMODE, bool BIAS, bool RELU, bool TCONV>
__global__ __launch_bounds__(256) void mfma_gemm(
    const u16* __restrict__ A, long aB, int aZdiv, int lda,
    const u16* __restrict__ Bm, long bB, int ldb, int bZmod,
    const float* __restrict__ bias, int biasStride,
    float* __restrict__ Cf, u16* __restrict__ Cn, long cB, int ldc,
    u16* __restrict__ Ct, long ctB, int ldct, int ctOff,
    int K, int dShift)
{
    __shared__ u16 sA[128 * 64];
    __shared__ u16 sB[128 * 64];
    const int z = blockIdx.z;
    const int zw = z / aZdiv;
    const int zb = z % bZmod;
    const int m0 = blockIdx.y * 128, n0 = blockIdx.x * 128;
    const int tid = threadIdx.x;
    const int lane = tid & 63, wv = tid >> 6;
    const int wm = wv >> 1, wn = wv & 1;
    const int l15 = lane & 15, l4 = lane >> 4;

    const u16* Ab = A + (long)zw * aB + (long)m0 * lda;
    const u16* Bb = Bm + (long)zb * bB + (long)n0 * ldb;

    const int srow = wv * 32 + (lane >> 3);
    const int sk16 = (lane & 7) ^ (lane >> 3);

    f32x4 acc[4][4];
    #pragma unroll
    for (int i = 0; i < 4; ++i)
        #pragma unroll
        for (int j = 0; j < 4; ++j) acc[i][j] = (f32x4){0.f, 0.f, 0.f, 0.f};

    for (int k0 = 0; k0 < K; k0 += 64) {
        int bCol = k0;
        int rOff = 0;
        if (TCONV) {
            const int kh = k0 >> 9;
            const int d = dShift ? dShift : 1 + (z >> 3);
            rOff = (kh - 1) * d;
            bCol = k0 & 511;
        }
        #pragma unroll
        for (int ch = 0; ch < 4; ++ch) {
            gload16(Ab + (long)(srow + ch * 8) * lda + k0 + sk16 * 8,
                    &sA[wv * 2048 + ch * 512]);
            gload16(Bb + (long)(srow + ch * 8 + rOff) * ldb + bCol + sk16 * 8,
                    &sB[wv * 2048 + ch * 512]);
        }
        __syncthreads();
        #pragma unroll
        for (int kk = 0; kk < 2; ++kk) {
            f16x8 af[4], bfr[4];
            #pragma unroll
            for (int f = 0; f < 4; ++f) {
                const int ra = wm * 64 + f * 16 + l15;
                af[f] = *(const f16x8*)&sA[ra * 64 + ((((kk << 2) | l4) ^ (ra & 7)) << 3)];
                const int rb = wn * 64 + f * 16 + l15;
                bfr[f] = *(const f16x8*)&sB[rb * 64 + ((((kk << 2) | l4) ^ (rb & 7)) << 3)];
            }
            #pragma unroll
            for (int mi = 0; mi < 4; ++mi)
                #pragma unroll
                for (int ni = 0; ni < 4; ++ni)
                    acc[mi][ni] = __builtin_amdgcn_mfma_f32_16x16x32_f16(
                        af[mi], bfr[ni], acc[mi][ni], 0, 0, 0);
        }
        __syncthreads();
    }

    #pragma unroll
    for (int mi = 0; mi < 4; ++mi) {
        const int mb = m0 + wm * 64 + mi * 16 + l4 * 4;
        float bv[4] = {0.f, 0.f, 0.f, 0.f};
        if (BIAS) {
            const float* bp = bias + (long)zw * biasStride;
            #pragma unroll
            for (int r = 0; r < 4; ++r) bv[r] = bp[mb + r];
        }
        #pragma unroll
        for (int ni = 0; ni < 4; ++ni) {
            const int nb = n0 + wn * 64 + ni * 16 + l15;
            float v[4];
            #pragma unroll
            for (int r = 0; r < 4; ++r) {
                v[r] = acc[mi][ni][r] + bv[r];
                if (RELU) v[r] = fmaxf(v[r], 0.f);
            }
            if (WMODE & 1) {
                #pragma unroll
                for (int r = 0; r < 4; ++r)
                    Cf[(long)z * cB + (long)(mb + r) * ldc + nb] = v[r];
            }
            if (WMODE & 2) {
                #pragma unroll
                for (int r = 0; r < 4; ++r)
                    Cn[(long)z * cB + (long)(mb + r) * ldc + nb] = f2h(v[r]);
            }
            if (WMODE & 4) {
                u16x4 pk;
                #pragma unroll
                for (int r = 0; r < 4; ++r) pk[r] = f2h(v[r]);
                *(u16x4*)&Ct[(long)z * ctB + (long)nb * ldct + ctOff + mb] = pk;
            }
        }
    }
}

// ---------------------------------------------------------------------------
// Flash attention v7 (split-KV, R16/R21-proven 206 us): each block handles
// HALF the KV range (16 iters). Grid (16, 24, 2) = 768 blocks = 3/CU balanced.
// Writes unnormalized O (f16) + per-row m,l; combine_kernel merges halves.
// ---------------------------------------------------------------------------
__global__ __launch_bounds__(512) void flash_attn(
    const u16* __restrict__ thA, const u16* __restrict__ phA,
    const u16* __restrict__ gxA, u16* __restrict__ oH,
    float* __restrict__ mH, float* __restrict__ lH)
{
    __shared__ u16 sK[64 * 256];     // [s][k]  32 KB, slot^(s&7) swizzle
    __shared__ u16 sV[256 * 64];     // [dv][s] 32 KB, slot^(dv&7) swizzle
    __shared__ u16 sP[8 * 16 * 64];  // per-wave [t][s] 16 KB, slot^(t&7)

    const int flat = (blockIdx.z * 24 + blockIdx.y) * 16 + blockIdx.x; // 0..767
    const int swz = (flat & 7) * 96 + (flat >> 3);   // 768 = 8 XCD x 96
    const int u = swz % 384;
    const int qb = u & 15, z = u >> 4;
    const int half = swz / 384;
    const int t0 = qb * 128;
    const int sBase = half * (T_ / 2);
    const int tid = threadIdx.x;
    const int lane = tid & 63, wv = tid >> 6;
    const int l15 = lane & 15, l4 = lane >> 4;

    const u16* Qz = thA + (long)z * (T_ * I_);
    const u16* Kz = phA + (long)z * (T_ * I_);
    const u16* Vz = gxA + (long)z * ((long)I_ * T_);

    // Q fragments in regs: rows t0 + wv*16 + l15, k = ks*32 + l4*8
    f16x8 qf[8];
    {
        const u16* qrow = Qz + (long)(t0 + wv * 16 + l15) * I_ + l4 * 8;
        #pragma unroll
        for (int ks = 0; ks < 8; ++ks) qf[ks] = *(const f16x8*)(qrow + ks * 32);
    }

    f32x4 oacc[16];
    #pragma unroll
    for (int i = 0; i < 16; ++i) oacc[i] = (f32x4){0.f, 0.f, 0.f, 0.f};
    float mrun[4] = {-1e30f, -1e30f, -1e30f, -1e30f};
    float lrun[4] = {0.f, 0.f, 0.f, 0.f};

    const int krow = tid >> 5;                    // + is*16
    const int kk16 = (tid & 31) ^ (krow & 7);
    const int vrow = tid >> 3;                    // + is*64
    const int vk16 = (tid & 7) ^ (vrow & 7);

    for (int s0 = sBase; s0 < sBase + T_ / 2; s0 += 64) {
        #pragma unroll
        for (int is = 0; is < 4; ++is) {
            gload16(Kz + (long)(s0 + is * 16 + krow) * I_ + kk16 * 8,
                    &sK[is * 4096 + tid * 8]);
            gload16(Vz + (long)(is * 64 + vrow) * T_ + s0 + vk16 * 8,
                    &sV[is * 4096 + tid * 8]);
        }
        __syncthreads();

        // S = Q K^T: rows t (wave's 16), cols s (64) = 4 n-frags
        f32x4 sacc[4];
        #pragma unroll
        for (int nf = 0; nf < 4; ++nf) sacc[nf] = (f32x4){0.f, 0.f, 0.f, 0.f};
        #pragma unroll
        for (int nf = 0; nf < 4; ++nf) {
            const int srow = nf * 16 + l15;
            #pragma unroll
            for (int ks = 0; ks < 8; ++ks) {
                f16x8 kf = *(const f16x8*)&sK[srow * 256 + ((((ks << 2) | l4) ^ (srow & 7)) << 3)];
                sacc[nf] = __builtin_amdgcn_mfma_f32_16x16x32_f16(qf[ks], kf, sacc[nf], 0, 0, 0);
            }
        }

        // online softmax; C/D row = l4*4+r, col = l15 + nf*16
        float scale[4];
        #pragma unroll
        for (int r = 0; r < 4; ++r) {
            float v0 = fmaxf(fmaxf(sacc[0][r], sacc[1][r]),
                             fmaxf(sacc[2][r], sacc[3][r]));
            #pragma unroll
            for (int o = 8; o; o >>= 1) v0 = fmaxf(v0, __shfl_xor(v0, o, 64));
            const float mnew = fmaxf(mrun[r], v0);
            scale[r] = __expf(mrun[r] - mnew);
            mrun[r] = mnew;
        }
        float rsum[4] = {0.f, 0.f, 0.f, 0.f};
        #pragma unroll
        for (int nf = 0; nf < 4; ++nf) {
            #pragma unroll
            for (int r = 0; r < 4; ++r) {
                const float p = __expf(sacc[nf][r] - mrun[r]);
                rsum[r] += p;
                const int tl = l4 * 4 + r;
                const int sl = l15 + nf * 16;
                sP[wv * 1024 + tl * 64 + ((((sl >> 3) ^ (tl & 7)) << 3) | (sl & 7))] = f2h(p);
            }
        }
        #pragma unroll
        for (int r = 0; r < 4; ++r) {
            #pragma unroll
            for (int o = 8; o; o >>= 1) rsum[r] += __shfl_xor(rsum[r], o, 64);
            lrun[r] = lrun[r] * scale[r] + rsum[r];
        }
        #pragma unroll
        for (int nf = 0; nf < 16; ++nf)
            #pragma unroll
            for (int r = 0; r < 4; ++r) oacc[nf][r] *= scale[r];

        // PV: A = P (row t = l15, k = s), B = V (row dv, k = s)
        f16x8 pa[2];
        #pragma unroll
        for (int kk = 0; kk < 2; ++kk)
            pa[kk] = *(const f16x8*)&sP[wv * 1024 + l15 * 64 + ((((kk << 2) | l4) ^ (l15 & 7)) << 3)];
        #pragma unroll
        for (int nf = 0; nf < 16; ++nf) {
            const int dvr = nf * 16 + l15;
            #pragma unroll
            for (int kk = 0; kk < 2; ++kk) {
                f16x8 vf = *(const f16x8*)&sV[dvr * 64 + ((((kk << 2) | l4) ^ (dvr & 7)) << 3)];
                oacc[nf] = __builtin_amdgcn_mfma_f32_16x16x32_f16(pa[kk], vf, oacc[nf], 0, 0, 0);
            }
        }
        __syncthreads();
    }

    // store UNNORMALIZED partials: oH[half][z][t][dv] (f16), mH/lH[half][z][t]
    #pragma unroll
    for (int r = 0; r < 4; ++r) {
        const int t = t0 + wv * 16 + l4 * 4 + r;
        const long row = ((long)half * 24 + z) * T_ + t;
        u16* dst = oH + row * I_ + l15;
        #pragma unroll
        for (int nf = 0; nf < 16; ++nf)
            dst[nf * 16] = f2h(oacc[nf][r]);
        if (l15 == 0) { mH[row] = mrun[r]; lH[row] = lrun[r]; }
    }
}

// combine: YT[b][t][br*I+dv] = (o0*e^{m0-m} + o1*e^{m1-m}) / (l0*e^{m0-m}+l1*e^{m1-m})
__global__ __launch_bounds__(256) void combine_kernel(
    const u16* __restrict__ oH, const float* __restrict__ mH,
    const float* __restrict__ lH, u16* __restrict__ YT)
{
    const long idx = (long)blockIdx.x * 256 + threadIdx.x;  // 24*T*(I/8)
    const int z = (int)(idx / (T_ * (I_ / 8)));
    const long rem = idx % (T_ * (I_ / 8));
    const int t = (int)(rem / (I_ / 8));
    const int dv0 = (int)(rem % (I_ / 8)) * 8;
    const long row0 = (long)z * T_ + t;
    const long row1 = ((long)24 + z) * T_ + t;
    const float m0 = mH[row0], m1 = mH[row1];
    const float l0 = lH[row0], l1 = lH[row1];
    const float m = fmaxf(m0, m1);
    const float a0 = __expf(m0 - m), a1 = __expf(m1 - m);
    const float inv = 1.f / (l0 * a0 + l1 * a1);
    const uint4 p0 = *(const uint4*)&oH[row0 * I_ + dv0];
    const uint4 p1 = *(const uint4*)&oH[row1 * I_ + dv0];
    const u16* b0 = (const u16*)&p0;
    const u16* b1 = (const u16*)&p1;
    uint4 ov;
    u16* bo = (u16*)&ov;
    #pragma unroll
    for (int j = 0; j < 8; ++j)
        bo[j] = f2h((h2f(b0[j]) * a0 + h2f(b1[j]) * a1) * inv);
    const int br = z >> 3, b = z & 7;
    *(uint4*)&YT[((long)b * T_ + t) * (3 * I_) + br * I_ + dv0] = ov;
}

// ---------------------------------------------------------------------------
__global__ __launch_bounds__(256) void to_f16(
    const float* __restrict__ s, u16* __restrict__ d, long n4)
{
    const long i = (long)blockIdx.x * 256 + threadIdx.x;
    if (i >= n4) return;
    const float4 v = ((const float4*)s)[i];
    u16x4 pk = {f2h(v.x), f2h(v.y), f2h(v.z), f2h(v.w)};
    ((u16x4*)d)[i] = pk;
}

__global__ __launch_bounds__(256) void peT_kernel(float* __restrict__ peT)
{
    const int idx = blockIdx.x * 256 + threadIdx.x;
    const int c = idx & (C_ - 1), t = idx >> 9;
    const float i2 = (float)(c & ~1);
    const float freq = expf(-(9.210340371976184f / (float)C_) * i2);
    const float ang = (float)t * freq;
    peT[idx] = (c & 1) ? cosf(ang) : sinf(ang);
}

__global__ __launch_bounds__(256) void xpose_add(
    const float* __restrict__ x, const float* __restrict__ peT,
    u16* __restrict__ xpeT)
{
    __shared__ float tile[64][65];
    const int b = blockIdx.z;
    const int t0 = blockIdx.x * 64, c0 = blockIdx.y * 64;
    const int rr = threadIdx.x >> 4, cc4 = (threadIdx.x & 15) << 2;
    #pragma unroll
    for (int p = 0; p < 4; ++p) {
        const int row = rr + p * 16;
        const float4 v = *(const float4*)&x[((long)b * C_ + c0 + row) * T_ + t0 + cc4];
        tile[row][cc4 + 0] = v.x; tile[row][cc4 + 1] = v.y;
        tile[row][cc4 + 2] = v.z; tile[row][cc4 + 3] = v.w;
    }
    __syncthreads();
    #pragma unroll
    for (int p = 0; p < 4; ++p) {
        const int tt = rr + p * 16;
        const int gt = t0 + tt;
        const float4 pv = *(const float4*)&peT[(long)gt * C_ + c0 + cc4];
        u16x4 pk = {f2h(tile[cc4 + 0][tt] + pv.x),
                    f2h(tile[cc4 + 1][tt] + pv.y),
                    f2h(tile[cc4 + 2][tt] + pv.z),
                    f2h(tile[cc4 + 3][tt] + pv.w)};
        *(u16x4*)&xpeT[((long)b * T_ + gt) * C_ + c0 + cc4] = pk;
    }
}

__global__ __launch_bounds__(256) void stats_kernel(
    const float* __restrict__ wy, float* __restrict__ mean,
    float* __restrict__ rstd)
{
    __shared__ float sm[8];
    const int o = blockIdx.x, tid = threadIdx.x;
    float s = 0.f, ss = 0.f;
    for (int idx = tid; idx < B_ * T_; idx += 256) {
        const int b = idx >> 11, t = idx & (T_ - 1);
        const float vv = wy[((long)b * C_ + o) * T_ + t];
        s += vv; ss += vv * vv;
    }
    #pragma unroll
    for (int off = 32; off; off >>= 1) {
        s += __shfl_xor(s, off, 64);
        ss += __shfl_xor(ss, off, 64);
    }
    if ((tid & 63) == 0) { sm[tid >> 6] = s; sm[4 + (tid >> 6)] = ss; }
    __syncthreads();
    if (tid == 0) {
        s = sm[0] + sm[1] + sm[2] + sm[3];
        ss = sm[4] + sm[5] + sm[6] + sm[7];
        const float mu = s / (float)(B_ * T_);
        const float var = ss / (float)(B_ * T_) - mu * mu;
        mean[o] = mu;
        rstd[o] = rsqrtf(var + 1e-5f);
    }
}

__global__ __launch_bounds__(256) void final_kernel(
    float* __restrict__ out, const u16* __restrict__ x1n,
    const float* __restrict__ mean, const float* __restrict__ rstd,
    const float* __restrict__ gamma, const float* __restrict__ beta)
{
    const long i4 = (long)blockIdx.x * 256 + threadIdx.x;
    const long i = i4 * 4;
    const int c = (int)((i / T_) & (C_ - 1));
    const float4 w = ((const float4*)out)[i4];
    const uint2 xv = ((const uint2*)x1n)[i4];
    const u16* xb = (const u16*)&xv;
    const float mu = mean[c];
    const float a = rstd[c] * gamma[c];
    const float bb = beta[c];
    float4 r;
    r.x = (w.x - mu) * a + bb + h2f(xb[0]);
    r.y = (w.y - mu) * a + bb + h2f(xb[1]);
    r.z = (w.z - mu) * a + bb + h2f(xb[2]);
    r.w = (w.w - mu) * a + bb + h2f(xb[3]);
    ((float4*)out)[i4] = r;
}

// ---------------------------------------------------------------------------
extern "C" void kernel_launch(void* const* d_in, const int* in_sizes, int n_in,
                              void* d_out, int out_size, void* d_ws, size_t ws_size,
                              hipStream_t stream)
{
    const float* x    = (const float*)d_in[0];
    const float* w_tr = (const float*)d_in[1];
    const float* b_tr = (const float*)d_in[2];
    const float* w_tc = (const float*)d_in[3];
    const float* w_g  = (const float*)d_in[4];
    const float* b_g  = (const float*)d_in[5];
    const float* w_th = (const float*)d_in[6];
    const float* b_th = (const float*)d_in[7];
    const float* w_ph = (const float*)d_in[8];
    const float* b_ph = (const float*)d_in[9];
    const float* w_W  = (const float*)d_in[10];
    const float* b_W  = (const float*)d_in[11];
    const float* gamma = (const float*)d_in[12];
    const float* beta  = (const float*)d_in[13];
    float* out = (float*)d_out;

    char* pp = (char*)d_ws;
    auto nextp = [&](long bytes) { char* r = pp; pp += (bytes + 255) & ~255L; return r; };
    const long TC  = (long)T_ * C_;
    const long CT  = (long)C_ * T_;
    const long TPC = (long)TP_ * C_;   // padded slab batch stride
    const long TI  = (long)T_ * I_;
    const long IT  = (long)I_ * T_;

    float* peT  = (float*)nextp(4L * T_ * C_);
    u16* xpeT   = (u16*)nextp(2L * B_ * TC);
    u16* x1n    = (u16*)nextp(2L * B_ * CT);
    u16* txAll  = (u16*)nextp(2L * 3 * B_ * TPC);  // (br, b, T+4, C), rows 2..T+1 valid
    u16* gxAll  = (u16*)nextp(2L * 3 * B_ * IT);   // (z, I, T)
    u16* thAll  = (u16*)nextp(2L * 3 * B_ * TI);   // (z, T, I); phAll contiguous after
    u16* phAll  = (u16*)nextp(2L * 3 * B_ * TI);
    u16* YT     = (u16*)nextp(2L * B_ * T_ * 3 * I_);
    u16* oH     = (u16*)nextp(2L * 2 * 24 * T_ * I_);   // split-KV partials
    float* mH   = (float*)nextp(4L * 2 * 24 * T_);
    float* lH   = (float*)nextp(4L * 2 * 24 * T_);
    u16* w_trb  = (u16*)nextp(2L * C_ * C_);
    u16* w_tcb  = (u16*)nextp(2L * 2 * C_ * 3 * C_);
    u16* w_gb   = (u16*)nextp(2L * 3 * I_ * C_);
    u16* w_thph = (u16*)nextp(2L * 6 * I_ * C_);   // [th(3,I,C); ph(3,I,C)]
    u16* w_Wb   = (u16*)nextp(2L * C_ * 3 * I_);
    float* biasAll = (float*)nextp(4L * 6 * I_);   // [b_th(3,I); b_ph(3,I)]
    float* meanb = (float*)nextp(4L * C_);
    float* rstdb = (float*)nextp(4L * C_);

    u16* slab0 = txAll;                 // tconv d=1 output (z=0..7)
    u16* slab2 = txAll + 2L * B_ * TPC; // x1 (branch 2 input + tconv B operand)

    auto cvt = [&](const float* s, u16* d, long n) {
        to_f16<<<(int)((n / 4 + 255) / 256), 256, 0, stream>>>(s, d, n / 4);
    };
    cvt(w_tr, w_trb, (long)C_ * C_);
    cvt(w_tc, w_tcb, 2L * C_ * 3 * C_);
    cvt(w_g,  w_gb,  3L * I_ * C_);
    cvt(w_th, w_thph, 3L * I_ * C_);
    cvt(w_ph, w_thph + 3L * I_ * C_, 3L * I_ * C_);
    cvt(w_W,  w_Wb,  (long)C_ * 3 * I_);
    hipMemcpyAsync(biasAll, b_th, 3L * I_ * 4, hipMemcpyDeviceToDevice, stream);
    hipMemcpyAsync(biasAll + 3 * I_, b_ph, 3L * I_ * 4, hipMemcpyDeviceToDevice, stream);

    peT_kernel<<<(T_ * C_) / 256, 256, 0, stream>>>(peT);
    xpose_add<<<dim3(T_ / 64, C_ / 64, B_), 256, 0, stream>>>(x, peT, xpeT);

    // zero x1 slab so its 2-row pads are 0 for shifted tconv reads
    hipMemsetAsync(slab2, 0, 2L * B_ * TPC, stream);

    // x1 = relu(w_tr @ xpe + b_tr) -> x1n (C,T) + padded slab2 (T,C at rows+2)
    mfma_gemm<6, true, true, false><<<dim3(16, 4, 8), 256, 0, stream>>>(
        w_trb, 0, 1, C_, xpeT, TC, C_, 9999, b_tr, 0,
        nullptr, x1n, CT, T_, slab2 + 2 * C_, TPC, C_, 0, C_, 0);

    // temporal convs MERGED: z = (d-1)*8 + b, grid.z = 16 (1024 blocks, 4/CU)
    mfma_gemm<4, false, false, true><<<dim3(16, 4, 16), 256, 0, stream>>>(
        w_tcb, (long)C_ * 3 * C_, 8, 3 * C_, slab2 + 2 * C_, TPC, C_, 8, nullptr, 0,
        nullptr, nullptr, 0, 0, slab0 + 2 * C_, TPC, C_, 0, 3 * C_, 0);

    // gx projection (grid.z = 24)
    mfma_gemm<2, true, false, false><<<dim3(16, 2, 24), 256, 0, stream>>>(
        w_gb, (long)I_ * C_, 8, C_, txAll + 2 * C_, TPC, C_, 9999, b_g, I_,
        nullptr, gxAll, IT, T_, nullptr, 0, 0, 0, C_, 0);

    // th+ph MERGED: z = proj*24 + br*8 + b, grid.z = 48 (1536 blocks, 6/CU)
    mfma_gemm<4, true, false, false><<<dim3(16, 2, 48), 256, 0, stream>>>(
        w_thph, (long)I_ * C_, 8, C_, txAll + 2 * C_, TPC, C_, 24, biasAll, I_,
        nullptr, nullptr, 0, 0, thAll, TI, I_, 0, C_, 0);

    // fused attention, split-KV (768 balanced blocks) + combine
    flash_attn<<<dim3(16, 24, 2), 512, 0, stream>>>(thAll, phAll, gxAll, oH, mH, lH);
    combine_kernel<<<(int)(24L * T_ * (I_ / 8) / 256), 256, 0, stream>>>(oH, mH, lH, YT);

    // wy = w_W @ Y + b_W -> d_out (f32)
    mfma_gemm<1, true, false, false><<<dim3(16, 4, 8), 256, 0, stream>>>(
        w_Wb, 0, 1, 3 * I_, YT, (long)T_ * 3 * I_, 3 * I_, 9999, b_W, 0,
        out, nullptr, CT, T_, nullptr, 0, 0, 0, 3 * I_, 0);

    stats_kernel<<<C_, 256, 0, stream>>>(out, meanb, rstdb);
    final_kernel<<<(int)(B_ * C_ * T_ / 4 / 256), 256, 0, stream>>>(
        out, x1n, meanb, rstdb, gamma, beta);
}

// Round 24
// 473.414 us; speedup vs baseline: 1.0580x; 1.0058x over previous
//
#include <hip/hip_runtime.h>

#define B_ 8
#define C_ 512
#define T_ 2048
#define I_ 256
#define TP_ (T_ + 4)   // padded time rows (2 each side) for shifted tconv reads

typedef _Float16 f16x8 __attribute__((ext_vector_type(8)));
typedef float f32x4 __attribute__((ext_vector_type(4)));
typedef unsigned short u16;
typedef unsigned short u16x4 __attribute__((ext_vector_type(4)));

__device__ __forceinline__ u16 f2h(float f) {
    _Float16 h = (_Float16)f;
    return *(u16*)&h;
}
__device__ __forceinline__ float h2f(u16 u) {
    _Float16 h = *(_Float16*)&u;
    return (float)h;
}

#define AS1 __attribute__((address_space(1)))
#define AS3 __attribute__((address_space(3)))
__device__ __forceinline__ void gload16(const u16* g, u16* l) {
    __builtin_amdgcn_global_load_lds((const AS1 void*)(const void*)g,
                                     (AS3 void*)(void*)l, 16, 0, 0);
}

// ---------------------------------------------------------------------------
// fp16 MFMA GEMM: out[z][m][n] = sum_k A[zw][m][k] * B[zb][n][k] (+ bias[zw][m])
//   zw = z / aZdiv (weight index), zb = z % bZmod (B-operand batch index).
//   TCONV: B row offset (kh-1)*d, kh = k0>>9; d = dShift, or 1+(z>>3) if
//   dShift==0 (merged dual-dilation dispatch). Output always indexed by z.
// Tile 128x128, BK=64, 256 thr = 4 waves. LDS slot^(row&7) swizzle.
// WMODE bits: 1 = f32 normal (Cf), 2 = f16 normal (Cn), 4 = f16 transposed (Ct).
// ---------------------------------------------------------------------------
template <int WMODE, bool BIAS, bool RELU, bool TCONV>
__global__ __launch_bounds__(256) void mfma_gemm(
    const u16* __restrict__ A, long aB, int aZdiv, int lda,
    const u16* __restrict__ Bm, long bB, int ldb, int bZmod,
    const float* __restrict__ bias, int biasStride,
    float* __restrict__ Cf, u16* __restrict__ Cn, long cB, int ldc,
    u16* __restrict__ Ct, long ctB, int ldct, int ctOff,
    int K, int dShift)
{
    __shared__ u16 sA[128 * 64];
    __shared__ u16 sB[128 * 64];
    const int z = blockIdx.z;
    const int zw = z / aZdiv;
    const int zb = z % bZmod;
    const int m0 = blockIdx.y * 128, n0 = blockIdx.x * 128;
    const int tid = threadIdx.x;
    const int lane = tid & 63, wv = tid >> 6;
    const int wm = wv >> 1, wn = wv & 1;
    const int l15 = lane & 15, l4 = lane >> 4;

    const u16* Ab = A + (long)zw * aB + (long)m0 * lda;
    const u16* Bb = Bm + (long)zb * bB + (long)n0 * ldb;

    const int srow = wv * 32 + (lane >> 3);
    const int sk16 = (lane & 7) ^ (lane >> 3);

    f32x4 acc[4][4];
    #pragma unroll
    for (int i = 0; i < 4; ++i)
        #pragma unroll
        for (int j = 0; j < 4; ++j) acc[i][j] = (f32x4){0.f, 0.f, 0.f, 0.f};

    for (int k0 = 0; k0 < K; k0 += 64) {
        int bCol = k0;
        int rOff = 0;
        if (TCONV) {
            const int kh = k0 >> 9;
            const int d = dShift ? dShift : 1 + (z >> 3);
            rOff = (kh - 1) * d;
            bCol = k0 & 511;
        }
        #pragma unroll
        for (int ch = 0; ch < 4; ++ch) {
            gload16(Ab + (long)(srow + ch * 8) * lda + k0 + sk16 * 8,
                    &sA[wv * 2048 + ch * 512]);
            gload16(Bb + (long)(srow + ch * 8 + rOff) * ldb + bCol + sk16 * 8,
                    &sB[wv * 2048 + ch * 512]);
        }
        __syncthreads();
        #pragma unroll
        for (int kk = 0; kk < 2; ++kk) {
            f16x8 af[4], bfr[4];
            #pragma unroll
            for (int f = 0; f < 4; ++f) {
                const int ra = wm * 64 + f * 16 + l15;
                af[f] = *(const f16x8*)&sA[ra * 64 + ((((kk << 2) | l4) ^ (ra & 7)) << 3)];
                const int rb = wn * 64 + f * 16 + l15;
                bfr[f] = *(const f16x8*)&sB[rb * 64 + ((((kk << 2) | l4) ^ (rb & 7)) << 3)];
            }
            #pragma unroll
            for (int mi = 0; mi < 4; ++mi)
                #pragma unroll
                for (int ni = 0; ni < 4; ++ni)
                    acc[mi][ni] = __builtin_amdgcn_mfma_f32_16x16x32_f16(
                        af[mi], bfr[ni], acc[mi][ni], 0, 0, 0);
        }
        __syncthreads();
    }

    #pragma unroll
    for (int mi = 0; mi < 4; ++mi) {
        const int mb = m0 + wm * 64 + mi * 16 + l4 * 4;
        float bv[4] = {0.f, 0.f, 0.f, 0.f};
        if (BIAS) {
            const float* bp = bias + (long)zw * biasStride;
            #pragma unroll
            for (int r = 0; r < 4; ++r) bv[r] = bp[mb + r];
        }
        #pragma unroll
        for (int ni = 0; ni < 4; ++ni) {
            const int nb = n0 + wn * 64 + ni * 16 + l15;
            float v[4];
            #pragma unroll
            for (int r = 0; r < 4; ++r) {
                v[r] = acc[mi][ni][r] + bv[r];
                if (RELU) v[r] = fmaxf(v[r], 0.f);
            }
            if (WMODE & 1) {
                #pragma unroll
                for (int r = 0; r < 4; ++r)
                    Cf[(long)z * cB + (long)(mb + r) * ldc + nb] = v[r];
            }
            if (WMODE & 2) {
                #pragma unroll
                for (int r = 0; r < 4; ++r)
                    Cn[(long)z * cB + (long)(mb + r) * ldc + nb] = f2h(v[r]);
            }
            if (WMODE & 4) {
                u16x4 pk;
                #pragma unroll
                for (int r = 0; r < 4; ++r) pk[r] = f2h(v[r]);
                *(u16x4*)&Ct[(long)z * ctB + (long)nb * ldct + ctOff + mb] = pk;
            }
        }
    }
}

// ---------------------------------------------------------------------------
// Flash attention v7 (split-KV, triple-validated 206 us): each block handles
// HALF the KV range (16 iters). Grid (16, 24, 2) = 768 blocks = 3/CU balanced.
// Writes unnormalized O (f16) + per-row m,l; combine_kernel merges halves.
// ---------------------------------------------------------------------------
__global__ __launch_bounds__(512) void flash_attn(
    const u16* __restrict__ thA, const u16* __restrict__ phA,
    const u16* __restrict__ gxA, u16* __restrict__ oH,
    float* __restrict__ mH, float* __restrict__ lH)
{
    __shared__ u16 sK[64 * 256];     // [s][k]  32 KB, slot^(s&7) swizzle
    __shared__ u16 sV[256 * 64];     // [dv][s] 32 KB, slot^(dv&7) swizzle
    __shared__ u16 sP[8 * 16 * 64];  // per-wave [t][s] 16 KB, slot^(t&7)

    const int flat = (blockIdx.z * 24 + blockIdx.y) * 16 + blockIdx.x; // 0..767
    const int swz = (flat & 7) * 96 + (flat >> 3);   // 768 = 8 XCD x 96
    const int u = swz % 384;
    const int qb = u & 15, z = u >> 4;
    const int half = swz / 384;
    const int t0 = qb * 128;
    const int sBase = half * (T_ / 2);
    const int tid = threadIdx.x;
    const int lane = tid & 63, wv = tid >> 6;
    const int l15 = lane & 15, l4 = lane >> 4;

    const u16* Qz = thA + (long)z * (T_ * I_);
    const u16* Kz = phA + (long)z * (T_ * I_);
    const u16* Vz = gxA + (long)z * ((long)I_ * T_);

    // Q fragments in regs: rows t0 + wv*16 + l15, k = ks*32 + l4*8
    f16x8 qf[8];
    {
        const u16* qrow = Qz + (long)(t0 + wv * 16 + l15) * I_ + l4 * 8;
        #pragma unroll
        for (int ks = 0; ks < 8; ++ks) qf[ks] = *(const f16x8*)(qrow + ks * 32);
    }

    f32x4 oacc[16];
    #pragma unroll
    for (int i = 0; i < 16; ++i) oacc[i] = (f32x4){0.f, 0.f, 0.f, 0.f};
    float mrun[4] = {-1e30f, -1e30f, -1e30f, -1e30f};
    float lrun[4] = {0.f, 0.f, 0.f, 0.f};

    const int krow = tid >> 5;                    // + is*16
    const int kk16 = (tid & 31) ^ (krow & 7);
    const int vrow = tid >> 3;                    // + is*64
    const int vk16 = (tid & 7) ^ (vrow & 7);

    for (int s0 = sBase; s0 < sBase + T_ / 2; s0 += 64) {
        #pragma unroll
        for (int is = 0; is < 4; ++is) {
            gload16(Kz + (long)(s0 + is * 16 + krow) * I_ + kk16 * 8,
                    &sK[is * 4096 + tid * 8]);
            gload16(Vz + (long)(is * 64 + vrow) * T_ + s0 + vk16 * 8,
                    &sV[is * 4096 + tid * 8]);
        }
        __syncthreads();

        // S = Q K^T: rows t (wave's 16), cols s (64) = 4 n-frags
        f32x4 sacc[4];
        #pragma unroll
        for (int nf = 0; nf < 4; ++nf) sacc[nf] = (f32x4){0.f, 0.f, 0.f, 0.f};
        #pragma unroll
        for (int nf = 0; nf < 4; ++nf) {
            const int srow = nf * 16 + l15;
            #pragma unroll
            for (int ks = 0; ks < 8; ++ks) {
                f16x8 kf = *(const f16x8*)&sK[srow * 256 + ((((ks << 2) | l4) ^ (srow & 7)) << 3)];
                sacc[nf] = __builtin_amdgcn_mfma_f32_16x16x32_f16(qf[ks], kf, sacc[nf], 0, 0, 0);
            }
        }

        // online softmax; C/D row = l4*4+r, col = l15 + nf*16
        float scale[4];
        #pragma unroll
        for (int r = 0; r < 4; ++r) {
            float v0 = fmaxf(fmaxf(sacc[0][r], sacc[1][r]),
                             fmaxf(sacc[2][r], sacc[3][r]));
            #pragma unroll
            for (int o = 8; o; o >>= 1) v0 = fmaxf(v0, __shfl_xor(v0, o, 64));
            const float mnew = fmaxf(mrun[r], v0);
            scale[r] = __expf(mrun[r] - mnew);
            mrun[r] = mnew;
        }
        float rsum[4] = {0.f, 0.f, 0.f, 0.f};
        #pragma unroll
        for (int nf = 0; nf < 4; ++nf) {
            #pragma unroll
            for (int r = 0; r < 4; ++r) {
                const float p = __expf(sacc[nf][r] - mrun[r]);
                rsum[r] += p;
                const int tl = l4 * 4 + r;
                const int sl = l15 + nf * 16;
                sP[wv * 1024 + tl * 64 + ((((sl >> 3) ^ (tl & 7)) << 3) | (sl & 7))] = f2h(p);
            }
        }
        #pragma unroll
        for (int r = 0; r < 4; ++r) {
            #pragma unroll
            for (int o = 8; o; o >>= 1) rsum[r] += __shfl_xor(rsum[r], o, 64);
            lrun[r] = lrun[r] * scale[r] + rsum[r];
        }
        #pragma unroll
        for (int nf = 0; nf < 16; ++nf)
            #pragma unroll
            for (int r = 0; r < 4; ++r) oacc[nf][r] *= scale[r];

        // PV: A = P (row t = l15, k = s), B = V (row dv, k = s)
        f16x8 pa[2];
        #pragma unroll
        for (int kk = 0; kk < 2; ++kk)
            pa[kk] = *(const f16x8*)&sP[wv * 1024 + l15 * 64 + ((((kk << 2) | l4) ^ (l15 & 7)) << 3)];
        #pragma unroll
        for (int nf = 0; nf < 16; ++nf) {
            const int dvr = nf * 16 + l15;
            #pragma unroll
            for (int kk = 0; kk < 2; ++kk) {
                f16x8 vf = *(const f16x8*)&sV[dvr * 64 + ((((kk << 2) | l4) ^ (dvr & 7)) << 3)];
                oacc[nf] = __builtin_amdgcn_mfma_f32_16x16x32_f16(pa[kk], vf, oacc[nf], 0, 0, 0);
            }
        }
        __syncthreads();
    }

    // store UNNORMALIZED partials: oH[half][z][t][dv] (f16), mH/lH[half][z][t]
    #pragma unroll
    for (int r = 0; r < 4; ++r) {
        const int t = t0 + wv * 16 + l4 * 4 + r;
        const long row = ((long)half * 24 + z) * T_ + t;
        u16* dst = oH + row * I_ + l15;
        #pragma unroll
        for (int nf = 0; nf < 16; ++nf)
            dst[nf * 16] = f2h(oacc[nf][r]);
        if (l15 == 0) { mH[row] = mrun[r]; lH[row] = lrun[r]; }
    }
}

// combine: YT[b][t][br*I+dv] = (o0*e^{m0-m} + o1*e^{m1-m}) / (l0*e^{m0-m}+l1*e^{m1-m})
__global__ __launch_bounds__(256) void combine_kernel(
    const u16* __restrict__ oH, const float* __restrict__ mH,
    const float* __restrict__ lH, u16* __restrict__ YT)
{
    const long idx = (long)blockIdx.x * 256 + threadIdx.x;  // 24*T*(I/8)
    const int z = (int)(idx / (T_ * (I_ / 8)));
    const long rem = idx % (T_ * (I_ / 8));
    const int t = (int)(rem / (I_ / 8));
    const int dv0 = (int)(rem % (I_ / 8)) * 8;
    const long row0 = (long)z * T_ + t;
    const long row1 = ((long)24 + z) * T_ + t;
    const float m0 = mH[row0], m1 = mH[row1];
    const float l0 = lH[row0], l1 = lH[row1];
    const float m = fmaxf(m0, m1);
    const float a0 = __expf(m0 - m), a1 = __expf(m1 - m);
    const float inv = 1.f / (l0 * a0 + l1 * a1);
    const uint4 p0 = *(const uint4*)&oH[row0 * I_ + dv0];
    const uint4 p1 = *(const uint4*)&oH[row1 * I_ + dv0];
    const u16* b0 = (const u16*)&p0;
    const u16* b1 = (const u16*)&p1;
    uint4 ov;
    u16* bo = (u16*)&ov;
    #pragma unroll
    for (int j = 0; j < 8; ++j)
        bo[j] = f2h((h2f(b0[j]) * a0 + h2f(b1[j]) * a1) * inv);
    const int br = z >> 3, b = z & 7;
    *(uint4*)&YT[((long)b * T_ + t) * (3 * I_) + br * I_ + dv0] = ov;
}

// ---------------------------------------------------------------------------
__global__ __launch_bounds__(256) void to_f16(
    const float* __restrict__ s, u16* __restrict__ d, long n4)
{
    const long i = (long)blockIdx.x * 256 + threadIdx.x;
    if (i >= n4) return;
    const float4 v = ((const float4*)s)[i];
    u16x4 pk = {f2h(v.x), f2h(v.y), f2h(v.z), f2h(v.w)};
    ((u16x4*)d)[i] = pk;
}

__global__ __launch_bounds__(256) void peT_kernel(float* __restrict__ peT)
{
    const int idx = blockIdx.x * 256 + threadIdx.x;
    const int c = idx & (C_ - 1), t = idx >> 9;
    const float i2 = (float)(c & ~1);
    const float freq = expf(-(9.210340371976184f / (float)C_) * i2);
    const float ang = (float)t * freq;
    peT[idx] = (c & 1) ? cosf(ang) : sinf(ang);
}

__global__ __launch_bounds__(256) void xpose_add(
    const float* __restrict__ x, const float* __restrict__ peT,
    u16* __restrict__ xpeT)
{
    __shared__ float tile[64][65];
    const int b = blockIdx.z;
    const int t0 = blockIdx.x * 64, c0 = blockIdx.y * 64;
    const int rr = threadIdx.x >> 4, cc4 = (threadIdx.x & 15) << 2;
    #pragma unroll
    for (int p = 0; p < 4; ++p) {
        const int row = rr + p * 16;
        const float4 v = *(const float4*)&x[((long)b * C_ + c0 + row) * T_ + t0 + cc4];
        tile[row][cc4 + 0] = v.x; tile[row][cc4 + 1] = v.y;
        tile[row][cc4 + 2] = v.z; tile[row][cc4 + 3] = v.w;
    }
    __syncthreads();
    #pragma unroll
    for (int p = 0; p < 4; ++p) {
        const int tt = rr + p * 16;
        const int gt = t0 + tt;
        const float4 pv = *(const float4*)&peT[(long)gt * C_ + c0 + cc4];
        u16x4 pk = {f2h(tile[cc4 + 0][tt] + pv.x),
                    f2h(tile[cc4 + 1][tt] + pv.y),
                    f2h(tile[cc4 + 2][tt] + pv.z),
                    f2h(tile[cc4 + 3][tt] + pv.w)};
        *(u16x4*)&xpeT[((long)b * T_ + gt) * C_ + c0 + cc4] = pk;
    }
}

__global__ __launch_bounds__(256) void stats_kernel(
    const float* __restrict__ wy, float* __restrict__ mean,
    float* __restrict__ rstd)
{
    __shared__ float sm[8];
    const int o = blockIdx.x, tid = threadIdx.x;
    float s = 0.f, ss = 0.f;
    for (int idx = tid; idx < B_ * T_; idx += 256) {
        const int b = idx >> 11, t = idx & (T_ - 1);
        const float vv = wy[((long)b * C_ + o) * T_ + t];
        s += vv; ss += vv * vv;
    }
    #pragma unroll
    for (int off = 32; off; off >>= 1) {
        s += __shfl_xor(s, off, 64);
        ss += __shfl_xor(ss, off, 64);
    }
    if ((tid & 63) == 0) { sm[tid >> 6] = s; sm[4 + (tid >> 6)] = ss; }
    __syncthreads();
    if (tid == 0) {
        s = sm[0] + sm[1] + sm[2] + sm[3];
        ss = sm[4] + sm[5] + sm[6] + sm[7];
        const float mu = s / (float)(B_ * T_);
        const float var = ss / (float)(B_ * T_) - mu * mu;
        mean[o] = mu;
        rstd[o] = rsqrtf(var + 1e-5f);
    }
}

__global__ __launch_bounds__(256) void final_kernel(
    float* __restrict__ out, const u16* __restrict__ x1n,
    const float* __restrict__ mean, const float* __restrict__ rstd,
    const float* __restrict__ gamma, const float* __restrict__ beta)
{
    const long i4 = (long)blockIdx.x * 256 + threadIdx.x;
    const long i = i4 * 4;
    const int c = (int)((i / T_) & (C_ - 1));
    const float4 w = ((const float4*)out)[i4];
    const uint2 xv = ((const uint2*)x1n)[i4];
    const u16* xb = (const u16*)&xv;
    const float mu = mean[c];
    const float a = rstd[c] * gamma[c];
    const float bb = beta[c];
    float4 r;
    r.x = (w.x - mu) * a + bb + h2f(xb[0]);
    r.y = (w.y - mu) * a + bb + h2f(xb[1]);
    r.z = (w.z - mu) * a + bb + h2f(xb[2]);
    r.w = (w.w - mu) * a + bb + h2f(xb[3]);
    ((float4*)out)[i4] = r;
}

// ---------------------------------------------------------------------------
extern "C" void kernel_launch(void* const* d_in, const int* in_sizes, int n_in,
                              void* d_out, int out_size, void* d_ws, size_t ws_size,
                              hipStream_t stream)
{
    const float* x    = (const float*)d_in[0];
    const float* w_tr = (const float*)d_in[1];
    const float* b_tr = (const float*)d_in[2];
    const float* w_tc = (const float*)d_in[3];
    const float* w_g  = (const float*)d_in[4];
    const float* b_g  = (const float*)d_in[5];
    const float* w_th = (const float*)d_in[6];
    const float* b_th = (const float*)d_in[7];
    const float* w_ph = (const float*)d_in[8];
    const float* b_ph = (const float*)d_in[9];
    const float* w_W  = (const float*)d_in[10];
    const float* b_W  = (const float*)d_in[11];
    const float* gamma = (const float*)d_in[12];
    const float* beta  = (const float*)d_in[13];
    float* out = (float*)d_out;

    char* pp = (char*)d_ws;
    auto nextp = [&](long bytes) { char* r = pp; pp += (bytes + 255) & ~255L; return r; };
    const long TC  = (long)T_ * C_;
    const long CT  = (long)C_ * T_;
    const long TPC = (long)TP_ * C_;   // padded slab batch stride
    const long TI  = (long)T_ * I_;
    const long IT  = (long)I_ * T_;

    float* peT  = (float*)nextp(4L * T_ * C_);
    u16* xpeT   = (u16*)nextp(2L * B_ * TC);
    u16* x1n    = (u16*)nextp(2L * B_ * CT);
    u16* txAll  = (u16*)nextp(2L * 3 * B_ * TPC);  // (br, b, T+4, C), rows 2..T+1 valid
    u16* gxAll  = (u16*)nextp(2L * 3 * B_ * IT);   // (z, I, T)
    u16* thAll  = (u16*)nextp(2L * 3 * B_ * TI);   // (z, T, I); phAll contiguous after
    u16* phAll  = (u16*)nextp(2L * 3 * B_ * TI);
    u16* YT     = (u16*)nextp(2L * B_ * T_ * 3 * I_);
    u16* oH     = (u16*)nextp(2L * 2 * 24 * T_ * I_);   // split-KV partials
    float* mH   = (float*)nextp(4L * 2 * 24 * T_);
    float* lH   = (float*)nextp(4L * 2 * 24 * T_);
    u16* w_trb  = (u16*)nextp(2L * C_ * C_);
    u16* w_tcb  = (u16*)nextp(2L * 2 * C_ * 3 * C_);
    u16* w_gb   = (u16*)nextp(2L * 3 * I_ * C_);
    u16* w_thph = (u16*)nextp(2L * 6 * I_ * C_);   // [th(3,I,C); ph(3,I,C)]
    u16* w_Wb   = (u16*)nextp(2L * C_ * 3 * I_);
    float* biasAll = (float*)nextp(4L * 6 * I_);   // [b_th(3,I); b_ph(3,I)]
    float* meanb = (float*)nextp(4L * C_);
    float* rstdb = (float*)nextp(4L * C_);

    u16* slab0 = txAll;                 // tconv d=1 output (z=0..7)
    u16* slab2 = txAll + 2L * B_ * TPC; // x1 (branch 2 input + tconv B operand)

    auto cvt = [&](const float* s, u16* d, long n) {
        to_f16<<<(int)((n / 4 + 255) / 256), 256, 0, stream>>>(s, d, n / 4);
    };
    cvt(w_tr, w_trb, (long)C_ * C_);
    cvt(w_tc, w_tcb, 2L * C_ * 3 * C_);
    cvt(w_g,  w_gb,  3L * I_ * C_);
    cvt(w_th, w_thph, 3L * I_ * C_);
    cvt(w_ph, w_thph + 3L * I_ * C_, 3L * I_ * C_);
    cvt(w_W,  w_Wb,  (long)C_ * 3 * I_);
    hipMemcpyAsync(biasAll, b_th, 3L * I_ * 4, hipMemcpyDeviceToDevice, stream);
    hipMemcpyAsync(biasAll + 3 * I_, b_ph, 3L * I_ * 4, hipMemcpyDeviceToDevice, stream);

    peT_kernel<<<(T_ * C_) / 256, 256, 0, stream>>>(peT);
    xpose_add<<<dim3(T_ / 64, C_ / 64, B_), 256, 0, stream>>>(x, peT, xpeT);

    // zero x1 slab so its 2-row pads are 0 for shifted tconv reads
    hipMemsetAsync(slab2, 0, 2L * B_ * TPC, stream);

    // x1 = relu(w_tr @ xpe + b_tr) -> x1n (C,T) + padded slab2 (T,C at rows+2)
    mfma_gemm<6, true, true, false><<<dim3(16, 4, 8), 256, 0, stream>>>(
        w_trb, 0, 1, C_, xpeT, TC, C_, 9999, b_tr, 0,
        nullptr, x1n, CT, T_, slab2 + 2 * C_, TPC, C_, 0, C_, 0);

    // temporal convs MERGED: z = (d-1)*8 + b, grid.z = 16 (1024 blocks, 4/CU)
    mfma_gemm<4, false, false, true><<<dim3(16, 4, 16), 256, 0, stream>>>(
        w_tcb, (long)C_ * 3 * C_, 8, 3 * C_, slab2 + 2 * C_, TPC, C_, 8, nullptr, 0,
        nullptr, nullptr, 0, 0, slab0 + 2 * C_, TPC, C_, 0, 3 * C_, 0);

    // gx projection (grid.z = 24)
    mfma_gemm<2, true, false, false><<<dim3(16, 2, 24), 256, 0, stream>>>(
        w_gb, (long)I_ * C_, 8, C_, txAll + 2 * C_, TPC, C_, 9999, b_g, I_,
        nullptr, gxAll, IT, T_, nullptr, 0, 0, 0, C_, 0);

    // th+ph MERGED: z = proj*24 + br*8 + b, grid.z = 48 (1536 blocks, 6/CU)
    mfma_gemm<4, true, false, false><<<dim3(16, 2, 48), 256, 0, stream>>>(
        w_thph, (long)I_ * C_, 8, C_, txAll + 2 * C_, TPC, C_, 24, biasAll, I_,
        nullptr, nullptr, 0, 0, thAll, TI, I_, 0, C_, 0);

    // fused attention, split-KV (768 balanced blocks) + combine
    flash_attn<<<dim3(16, 24, 2), 512, 0, stream>>>(thAll, phAll, gxAll, oH, mH, lH);
    combine_kernel<<<(int)(24L * T_ * (I_ / 8) / 256), 256, 0, stream>>>(oH, mH, lH, YT);

    // wy = w_W @ Y + b_W -> d_out (f32)
    mfma_gemm<1, true, false, false><<<dim3(16, 4, 8), 256, 0, stream>>>(
        w_Wb, 0, 1, 3 * I_, YT, (long)T_ * 3 * I_, 3 * I_, 9999, b_W, 0,
        out, nullptr, CT, T_, nullptr, 0, 0, 0, 3 * I_, 0);

    stats_kernel<<<C_, 256, 0, stream>>>(out, meanb, rstdb);
    final_kernel<<<(int)(B_ * C_ * T_ / 4 / 256), 256, 0, stream>>>(
        out, x1n, meanb, rstdb, gamma, beta);
}